// Round 2
// baseline (229.121 us; speedup 1.0000x reference)
//
#include <hip/hip_runtime.h>
#include <math.h>

// ---------------------------------------------------------------------------
// TransNeXt aggregated attention. Round 13:
//  - All MFMA GEMMs rebuilt: LDS XOR-swizzle (conflict-free ds_read_b128,
//    pre-swizzled global source + swizzled read per rule "both sides or
//    neither"), 2-phase double-buffered K-loop (1 barrier/K-step, loads for
//    k+1 in flight under MFMA of k).
//  - x-GEMM widened to 128x128 tile (16 MFMA/K-step, A re-reads halved).
//  6 dispatches.
// B=4, H=W=64, C=256, NH=8, hd=32, LOCAL_LEN=9, pool 8x8=64
// ---------------------------------------------------------------------------

typedef unsigned short ushort_t;
typedef __attribute__((ext_vector_type(8))) _Float16 half8;
typedef __attribute__((ext_vector_type(2))) _Float16 half2_t;
typedef __attribute__((ext_vector_type(4))) float f32x4;

static __device__ __forceinline__ ushort_t f2h(float f) {
    _Float16 h = (_Float16)f;           // RTNE
    return *(ushort_t*)&h;
}

static __device__ __forceinline__ float fdot2f(half2_t a, half2_t b, float c) {
#if __has_builtin(__builtin_amdgcn_fdot2)
    return __builtin_amdgcn_fdot2(a, b, c, false);
#else
    return (float)a[0] * (float)b[0] + (float)a[1] * (float)b[1] + c;
#endif
}

// ---- DPP lane reductions (VALU pipe) --------------------------------------
template <int CTRL>
static __device__ __forceinline__ float dpp_addf(float x) {
    int v = __builtin_amdgcn_update_dpp(
        0, __builtin_bit_cast(int, x), CTRL, 0xF, 0xF, true);
    return x + __builtin_bit_cast(float, v);
}
static __device__ __forceinline__ float quad_sumf(float x) {
    return dpp_addf<0x4E>(dpp_addf<0xB1>(x));
}
static __device__ __forceinline__ float sum16f(float x) {
    return dpp_addf<0x128>(dpp_addf<0x124>(quad_sumf(x)));
}

#define GLOAD16(g, l)                                                        \
    __builtin_amdgcn_global_load_lds(                                        \
        (const __attribute__((address_space(1))) unsigned int*)(g),          \
        (__attribute__((address_space(3))) unsigned int*)(l), 16, 0, 0)

// ---------------------------------------------------------------------------
// mfma_hgemm<TM,TN>: C = A @ W^T + bias, fp16 in, fp32 accum.
// 4 waves in 2x2; wave tile (TM/2)x(TN/2). Double-buffered LDS, XOR-swizzled.
// mode 0 (x-GEMM, N=1024): col<256 -> qh fp16; col<512 -> kvh k fp16 with
//   FUSED per-head L2 norm; col<768 -> kvh v fp16; else gelu -> xsrh fp16
// mode 1 (proj, N=256): out0 fp32
// mode 2 (kv_p, N=512): kvh (stride 512) fp16; col<256 fused per-head L2 norm
//
// LDS swizzle: logical element (row, 16B-slot s) stored at phys slot
// s ^ ((row>>1)&3). Stage keeps LDS dest linear (global_load_lds constraint)
// and pre-swizzles the GLOBAL source column; reads apply the same XOR.
// Lanes 0..7 of a b128 read then cover slots {0,4,1,5,2,6,3,7}: conflict-free.
// ---------------------------------------------------------------------------
template <int TM, int TN>
__global__ __launch_bounds__(256) void mfma_hgemm(
    const ushort_t* __restrict__ Ag, const ushort_t* __restrict__ Bg,
    const float* __restrict__ bias, float* __restrict__ out0,
    ushort_t* __restrict__ qh_out, ushort_t* __restrict__ kvh,
    ushort_t* __restrict__ xsrh, int mode)
{
    const int K = 256;
    const int IM = TM / 32;
    const int JN = TN / 32;
    __shared__ ushort_t Ah[2][TM * 32];
    __shared__ ushort_t Bh[2][TN * 32];

    const int t = threadIdx.x;
    const int w = t >> 6;
    const int lane = t & 63;
    const int bm = blockIdx.y * TM;
    const int bn = blockIdx.x * TN;
    const int wm = (w >> 1) * (TM / 2);
    const int wn = (w & 1) * (TN / 2);

    f32x4 acc[IM][JN];
#pragma unroll
    for (int i = 0; i < IM; ++i)
#pragma unroll
        for (int j = 0; j < JN; ++j) acc[i][j] = f32x4{0.f, 0.f, 0.f, 0.f};

    const int lrow  = t >> 2;
    const int lk8sw = ((t & 3) ^ ((t >> 3) & 3)) * 8;  // pre-swizzled src col

#define STAGE(bufi, k0s)                                                     \
    do {                                                                     \
        _Pragma("unroll")                                                    \
        for (int r = 0; r < TM / 64; ++r)                                    \
            GLOAD16(Ag + (size_t)(bm + r * 64 + lrow) * K + (k0s) + lk8sw,   \
                    &Ah[bufi][(unsigned)(r * 64 + w * 16) * 32]);            \
        _Pragma("unroll")                                                    \
        for (int r = 0; r < TN / 64; ++r)                                    \
            GLOAD16(Bg + (size_t)(bn + r * 64 + lrow) * K + (k0s) + lk8sw,   \
                    &Bh[bufi][(unsigned)(r * 64 + w * 16) * 32]);            \
    } while (0)

    const int fr   = lane & 15;
    const int sws8 = ((lane >> 4) ^ ((fr >> 1) & 3)) * 8;  // swizzled read slot

    STAGE(0, 0);
    __syncthreads();
    int buf = 0;
    for (int k0 = 0; k0 < K; k0 += 32) {
        if (k0 + 32 < K) STAGE(buf ^ 1, k0 + 32);

        half8 af[IM], bf[JN];
#pragma unroll
        for (int i = 0; i < IM; ++i)
            af[i] = *(const half8*)&Ah[buf][(unsigned)(wm + i * 16 + fr) * 32 + sws8];
#pragma unroll
        for (int j = 0; j < JN; ++j)
            bf[j] = *(const half8*)&Bh[buf][(unsigned)(wn + j * 16 + fr) * 32 + sws8];
#pragma unroll
        for (int i = 0; i < IM; ++i)
#pragma unroll
            for (int j = 0; j < JN; ++j)
                acc[i][j] = __builtin_amdgcn_mfma_f32_16x16x32_f16(af[i], bf[j], acc[i][j], 0, 0, 0);

        __syncthreads();
        buf ^= 1;
    }
#undef STAGE

    // epilogue: C/D layout col=lane&15, row=(lane>>4)*4+reg.
    // A 32-col (jp) group is one head; sum16f over the 16-lane row covers
    // its 32 cols at uniform output row -> fused L2 norm.
    const int q4 = (lane >> 4) * 4;
#pragma unroll
    for (int i = 0; i < IM; ++i) {
#pragma unroll
        for (int jp = 0; jp < JN / 2; ++jp) {
#pragma unroll
            for (int r = 0; r < 4; ++r) {
                const int row = bm + wm + i * 16 + q4 + r;
                const int col0 = bn + wn + jp * 32 + fr;
                const int col1 = col0 + 16;
                float v0 = acc[i][2 * jp][r] + bias[col0];
                float v1 = acc[i][2 * jp + 1][r] + bias[col1];
                if (mode == 0) {
                    if (col0 < 256) {
                        qh_out[(size_t)row * 256 + col0] = f2h(v0);
                        qh_out[(size_t)row * 256 + col1] = f2h(v1);
                    } else if (col0 < 512) {   // k: fused per-head L2 norm
                        const float ss = sum16f(v0 * v0 + v1 * v1);
                        const float invn = 1.0f / fmaxf(sqrtf(ss), 1e-12f);
                        kvh[(size_t)row * 512 + (col0 - 256)] = f2h(v0 * invn);
                        kvh[(size_t)row * 512 + (col1 - 256)] = f2h(v1 * invn);
                    } else if (col0 < 768) {   // v
                        kvh[(size_t)row * 512 + (col0 - 256)] = f2h(v0);
                        kvh[(size_t)row * 512 + (col1 - 256)] = f2h(v1);
                    } else {                    // sr + gelu
                        v0 = 0.5f * v0 * (1.0f + erff(v0 * 0.70710678118654752f));
                        v1 = 0.5f * v1 * (1.0f + erff(v1 * 0.70710678118654752f));
                        xsrh[(size_t)row * 256 + (col0 - 768)] = f2h(v0);
                        xsrh[(size_t)row * 256 + (col1 - 768)] = f2h(v1);
                    }
                } else if (mode == 2) {         // kv_p: fp16 out, stride 512
                    if (col0 < 256) {           // k_pool: fused per-head norm
                        const float ss = sum16f(v0 * v0 + v1 * v1);
                        const float invn = 1.0f / fmaxf(sqrtf(ss), 1e-12f);
                        v0 *= invn; v1 *= invn;
                    }
                    kvh[(size_t)row * 512 + col0] = f2h(v0);
                    kvh[(size_t)row * 512 + col1] = f2h(v1);
                } else {
                    out0[(size_t)row * 256 + col0] = v0;
                    out0[(size_t)row * 256 + col1] = v1;
                }
            }
        }
    }
}

// prep_cpb: x fp32->fp16 cast + weight/bias packing + cpb MLP in one kernel.
// Blocks [0, nprep): prep. Blocks [nprep, nprep+ncpb): cpb (wave per row).
__global__ __launch_bounds__(256) void prep_cpb(
    const float4* __restrict__ x, ushort4* __restrict__ xh, int n4, int nprep,
    const float* __restrict__ qw, const float* __restrict__ kvw,
    const float* __restrict__ srw, const float* __restrict__ pw,
    const float* __restrict__ qb, const float* __restrict__ kvb,
    const float* __restrict__ srb,
    ushort_t* __restrict__ Wall, ushort_t* __restrict__ Pw,
    float* __restrict__ ball,
    const float* __restrict__ table, const float* __restrict__ w1,
    const float* __restrict__ b1, const float* __restrict__ w2,
    const float* __restrict__ b2, float* __restrict__ outc, int T)
{
    if (blockIdx.x >= nprep) {
        const int wv = threadIdx.x >> 6;
        const int lane = threadIdx.x & 63;
        const int row = (blockIdx.x - nprep) * 4 + wv;
        if (row >= T) return;
        const float t0 = table[(size_t)row * 2];
        const float t1 = table[(size_t)row * 2 + 1];
        const int base = lane * 8;

        const float4* w1p = (const float4*)(w1 + (size_t)base * 2);
        float4 wa = w1p[0], wb = w1p[1], wc = w1p[2], wd = w1p[3];
        float4 ba = *(const float4*)(b1 + base);
        float4 bb = *(const float4*)(b1 + base + 4);
        float h[8];
        h[0] = fmaxf(fmaf(t1, wa.y, fmaf(t0, wa.x, ba.x)), 0.f);
        h[1] = fmaxf(fmaf(t1, wa.w, fmaf(t0, wa.z, ba.y)), 0.f);
        h[2] = fmaxf(fmaf(t1, wb.y, fmaf(t0, wb.x, ba.z)), 0.f);
        h[3] = fmaxf(fmaf(t1, wb.w, fmaf(t0, wb.z, ba.w)), 0.f);
        h[4] = fmaxf(fmaf(t1, wc.y, fmaf(t0, wc.x, bb.x)), 0.f);
        h[5] = fmaxf(fmaf(t1, wc.w, fmaf(t0, wc.z, bb.y)), 0.f);
        h[6] = fmaxf(fmaf(t1, wd.y, fmaf(t0, wd.x, bb.z)), 0.f);
        h[7] = fmaxf(fmaf(t1, wd.w, fmaf(t0, wd.z, bb.w)), 0.f);

#pragma unroll
        for (int hh = 0; hh < 8; ++hh) {
            const float4* w2p = (const float4*)(w2 + (size_t)hh * 512 + base);
            float4 p0 = w2p[0], p1 = w2p[1];
            float s = h[0]*p0.x + h[1]*p0.y + h[2]*p0.z + h[3]*p0.w
                    + h[4]*p1.x + h[5]*p1.y + h[6]*p1.z + h[7]*p1.w;
#pragma unroll
            for (int off = 1; off <= 32; off <<= 1) s += __shfl_xor(s, off);
            if (lane == 0) outc[(size_t)row * 8 + hh] = s + b2[hh];
        }
        return;
    }

    int idx = blockIdx.x * 256 + threadIdx.x;
    if (idx < n4) {
        float4 v = x[idx];
        ushort4 h;
        h.x = f2h(v.x); h.y = f2h(v.y); h.z = f2h(v.z); h.w = f2h(v.w);
        xh[idx] = h;
    }
    if (idx < 262144) {
        int nn = idx >> 8, k = idx & 255;
        float a;
        if (nn < 256)      a = qw[nn * 256 + k];
        else if (nn < 768) a = kvw[(nn - 256) * 256 + k];
        else               a = srw[(nn - 768) * 256 + k];
        Wall[idx] = f2h(a);
    }
    if (idx < 65536) Pw[idx] = f2h(pw[idx]);
    if (idx < 1024) {
        float bv;
        if (idx < 256)      bv = qb[idx];
        else if (idx < 768) bv = kvb[idx - 256];
        else                bv = srb[idx - 768];
        ball[idx] = bv;
    }
}

// 8x8 average pool of x_sr fp16 (B,N,C) + LayerNorm -> xpool fp16 (B,64,C)
__global__ __launch_bounds__(256) void pool_ln(
    const ushort_t* __restrict__ xsr, const float* __restrict__ g,
    const float* __restrict__ be, ushort_t* __restrict__ xpool, int Hh, int Ww)
{
    const int C = 256;
    const int Nn = Hh * Ww;
    int b = blockIdx.x >> 6;
    int pidx = blockIdx.x & 63;
    int ph = pidx >> 3, pw = pidx & 7;
    int tid = threadIdx.x;
    float s = 0.f;
    for (int si = 0; si < 8; ++si) {
        int i = ph * 8 + si;
        const ushort_t* rowp = xsr + ((size_t)b * Nn + (size_t)i * Ww + pw * 8) * C + tid;
#pragma unroll
        for (int sj = 0; sj < 8; ++sj)
            s += (float)(*(const _Float16*)&rowp[(size_t)sj * C]);
    }
    s *= (1.f / 64.f);
    __shared__ float red[256];
    red[tid] = s; __syncthreads();
    for (int st = 128; st; st >>= 1) { if (tid < st) red[tid] += red[tid + st]; __syncthreads(); }
    float mean = red[0] * (1.f / 256.f);
    __syncthreads();
    float dv = s - mean;
    red[tid] = dv * dv; __syncthreads();
    for (int st = 128; st; st >>= 1) { if (tid < st) red[tid] += red[tid + st]; __syncthreads(); }
    float var = red[0] * (1.f / 256.f);
    xpool[(size_t)blockIdx.x * C + tid] = f2h(dv * rsqrtf(var + 1e-5f) * g[tid] + be[tid]);
}

// ---------------------------------------------------------------------------
// attn_v8: lane-quad per query; fp16 q/K/V/k_pool/v_pool; DPP reductions;
// pool bias gathered per block (rpi -> cpbB) into padded LDS fp16 tile.
// ---------------------------------------------------------------------------
__global__ __launch_bounds__(256) void attn_v8(
    const ushort_t* __restrict__ qh_g, // (B,N,256) fp16 raw q
    const ushort_t* __restrict__ kvh,  // (B,N,512) fp16: k normed | v
    const ushort_t* __restrict__ kvph, // (B,64,512) fp16: k_pool normed | v_pool
    const int* __restrict__ rpi,       // (N*64) table index
    const float* __restrict__ cpbB,    // (T,8) cpb output
    const float* __restrict__ sls, const float* __restrict__ temp,
    const float* __restrict__ qe, const float* __restrict__ rbl,
    const float* __restrict__ ltok, const float* __restrict__ lbias,
    ushort_t* __restrict__ attno_hf)   // (B,N,256) fp16
{
    const int h = blockIdx.y, b = blockIdx.z;
    const int t = threadIdx.x;
    const int i = blockIdx.x;

    __shared__ half8 kp_s[64][4];
    __shared__ half8 vp_s[64][4];
    __shared__ ushort_t pb_s[64][66];   // [query j][pool p], pad 66 -> no bank conflict
    __shared__ float lts[9][32];
    __shared__ float rbl_s[9], lb_s[9], qe_s[32];

    {
        const int p = t >> 2;
        const int g4s = t & 3;
        const ushort_t* gk = kvph + ((size_t)(b * 64 + p)) * 512 + h * 32 + g4s * 8;
        kp_s[p][g4s] = *(const half8*)gk;
        vp_s[p][g4s] = *(const half8*)(gk + 256);
        const int rbase = i * 4096;
        for (int u = t; u < 4096; u += 256) {
            const int idx = rpi[rbase + u];
            pb_s[u >> 6][u & 63] = f2h(cpbB[(size_t)idx * 8 + h]);
        }
        for (int u = t; u < 288; u += 256) lts[u % 9][u / 9] = ltok[h * 288 + u];
        if (t < 9)  { rbl_s[t] = rbl[h * 9 + t]; lb_s[t] = lbias[h * 9 + t]; }
        if (t >= 64 && t < 96) qe_s[t - 64] = qe[h * 32 + (t - 64)];
    }
    __syncthreads();

    const int w = t >> 6;
    const int lane = t & 63;
    const int qi = lane >> 2;
    const int g4 = lane & 3;
    const int co = g4 * 8;
    const int j = w * 16 + qi;
    const int n = i * 64 + j;
    const size_t gq = (size_t)b * 4096 + n;

    const float tm = temp[h];
    const float sp = (tm > 20.f) ? tm : log1pf(expf(tm));

    // ---- load q slice (fp16), L2-normalize (quad DPP reduce) ----
    float qv[8];
    {
        const half8 q8 = *(const half8*)(qh_g + gq * 256 + h * 32 + co);
        float ss = 0.f;
#pragma unroll
        for (int d = 0; d < 8; ++d) { qv[d] = (float)q8[d]; ss += qv[d] * qv[d]; }
        ss = quad_sumf(ss);
        const float invn = 1.0f / fmaxf(sqrtf(ss), 1e-12f);
#pragma unroll
        for (int d = 0; d < 8; ++d) qv[d] *= invn;
    }

    // ---- learnable-token dots (fp32) ----
    float lt[9];
#pragma unroll
    for (int l = 0; l < 9; ++l) {
        float dl = 0.f;
        const float4* lw = (const float4*)&lts[l][co];
#pragma unroll
        for (int c4 = 0; c4 < 2; ++c4) {
            float4 w4 = lw[c4];
            dl += qv[4*c4+0]*w4.x + qv[4*c4+1]*w4.y + qv[4*c4+2]*w4.z + qv[4*c4+3]*w4.w;
        }
        dl = quad_sumf(dl);
        lt[l] = dl + lb_s[l];
    }

    // ---- scaled q -> fp16 pairs ----
    const float scal = sp * sls[n];
    half2_t qh[4];
#pragma unroll
    for (int c = 0; c < 4; ++c) {
        float a = (qv[2*c+0] + qe_s[co + 2*c+0]) * scal;
        float bq = (qv[2*c+1] + qe_s[co + 2*c+1]) * scal;
        qh[c] = half2_t{(_Float16)a, (_Float16)bq};
    }

    // ---- local scores (fp16 k, fdot2) ----
    float sl[9];
#pragma unroll
    for (int l = 0; l < 9; ++l) {
        const int di = l / 3 - 1, dj = l % 3 - 1;
        const int ii = i + di;
        const int jn = j + dj;
        const bool ok = (ii >= 0) && (ii < 64) && (jn >= 0) && (jn < 64);
        const int ic = max(min(ii, 63), 0);
        const int jc = max(min(jn, 63), 0);
        const half8 k8 = *(const half8*)(kvh + ((size_t)(b * 4096 + ic * 64 + jc)) * 512 + h * 32 + co);
        float dk = 0.f;
        dk = fdot2f(qh[0], __builtin_shufflevector(k8, k8, 0, 1), dk);
        dk = fdot2f(qh[1], __builtin_shufflevector(k8, k8, 2, 3), dk);
        dk = fdot2f(qh[2], __builtin_shufflevector(k8, k8, 4, 5), dk);
        dk = fdot2f(qh[3], __builtin_shufflevector(k8, k8, 6, 7), dk);
        dk = quad_sumf(dk);
        sl[l] = ok ? (dk + rbl_s[l]) : -INFINITY;
    }

    float m = sl[0];
#pragma unroll
    for (int l = 1; l < 9; ++l) m = fmaxf(m, sl[l]);

    // ---- pool: 8 chunks of 8, online softmax; AV in packed fp16 ----
    half2_t oh[4];
#pragma unroll
    for (int c = 0; c < 4; ++c) oh[c] = half2_t{(_Float16)0.f, (_Float16)0.f};
    float Z = 0.f;

    for (int cch = 0; cch < 8; ++cch) {
        float s8[8];
        float pbv[8];
#pragma unroll
        for (int c = 0; c < 4; ++c) {
            const half2_t p2 = *(const half2_t*)&pb_s[j][cch * 8 + 2 * c];
            pbv[2*c]   = (float)p2[0];
            pbv[2*c+1] = (float)p2[1];
        }
#pragma unroll
        for (int k = 0; k < 8; ++k) {
            const int p = cch * 8 + k;
            const half8 k8 = kp_s[p][g4];
            float acc = 0.f;
            acc = fdot2f(qh[0], __builtin_shufflevector(k8, k8, 0, 1), acc);
            acc = fdot2f(qh[1], __builtin_shufflevector(k8, k8, 2, 3), acc);
            acc = fdot2f(qh[2], __builtin_shufflevector(k8, k8, 4, 5), acc);
            acc = fdot2f(qh[3], __builtin_shufflevector(k8, k8, 6, 7), acc);
            acc = quad_sumf(acc);
            s8[k] = acc + pbv[k];
        }
        float cmax = s8[0];
#pragma unroll
        for (int k = 1; k < 8; ++k) cmax = fmaxf(cmax, s8[k]);
        const float m_new = fmaxf(m, cmax);
        const float factor = __expf(m - m_new);
        Z *= factor;
        const _Float16 fh = (_Float16)factor;
        const half2_t f2 = half2_t{fh, fh};
#pragma unroll
        for (int c = 0; c < 4; ++c) oh[c] *= f2;
        m = m_new;
#pragma unroll
        for (int k = 0; k < 8; ++k) {
            const float a = __expf(s8[k] - m);
            Z += a;
            const _Float16 ah = (_Float16)a;
            const half2_t a2 = half2_t{ah, ah};
            const half8 v8 = vp_s[cch * 8 + k][g4];
            oh[0] = a2 * __builtin_shufflevector(v8, v8, 0, 1) + oh[0];
            oh[1] = a2 * __builtin_shufflevector(v8, v8, 2, 3) + oh[1];
            oh[2] = a2 * __builtin_shufflevector(v8, v8, 4, 5) + oh[2];
            oh[3] = a2 * __builtin_shufflevector(v8, v8, 6, 7) + oh[3];
        }
    }

    // ---- local exps with final m ----
#pragma unroll
    for (int l = 0; l < 9; ++l) { sl[l] = __expf(sl[l] - m); Z += sl[l]; }

    // ---- local AV: coef = el + lt*Z (unnormalized; final *invZ) ----
#pragma unroll
    for (int l = 0; l < 9; ++l) {
        const int di = l / 3 - 1, dj = l % 3 - 1;
        const int ii = i + di;
        const int jn = j + dj;
        const bool ok = (ii >= 0) && (ii < 64) && (jn >= 0) && (jn < 64);
        const int ic = max(min(ii, 63), 0);
        const int jc = max(min(jn, 63), 0);
        const float coef = ok ? (sl[l] + lt[l] * Z) : 0.f;
        const half8 v8 = *(const half8*)(kvh + ((size_t)(b * 4096 + ic * 64 + jc)) * 512 + 256 + h * 32 + co);
        const _Float16 ch = (_Float16)coef;
        const half2_t c2 = half2_t{ch, ch};
        oh[0] = c2 * __builtin_shufflevector(v8, v8, 0, 1) + oh[0];
        oh[1] = c2 * __builtin_shufflevector(v8, v8, 2, 3) + oh[1];
        oh[2] = c2 * __builtin_shufflevector(v8, v8, 4, 5) + oh[2];
        oh[3] = c2 * __builtin_shufflevector(v8, v8, 6, 7) + oh[3];
    }

    // ---- normalize and store fp16 ----
    const float invZ = 1.0f / Z;
    ushort4* outp = (ushort4*)(attno_hf + gq * 256 + h * 32 + co);
#pragma unroll
    for (int c4 = 0; c4 < 2; ++c4) {
        ushort4 u;
        u.x = f2h((float)oh[2*c4+0][0] * invZ);
        u.y = f2h((float)oh[2*c4+0][1] * invZ);
        u.z = f2h((float)oh[2*c4+1][0] * invZ);
        u.w = f2h((float)oh[2*c4+1][1] * invZ);
        outp[c4] = u;
    }
}

extern "C" void kernel_launch(void* const* d_in, const int* in_sizes, int n_in,
                              void* d_out, int out_size, void* d_ws, size_t ws_size,
                              hipStream_t stream)
{
    const float* x    = (const float*)d_in[0];
    const float* tbl  = (const float*)d_in[1];
    const float* sls  = (const float*)d_in[2];
    const float* q_w  = (const float*)d_in[3];
    const float* q_b  = (const float*)d_in[4];
    const float* kv_w = (const float*)d_in[5];
    const float* kv_b = (const float*)d_in[6];
    const float* temp = (const float*)d_in[7];
    const float* qe   = (const float*)d_in[8];
    const float* sr_w = (const float*)d_in[9];
    const float* sr_b = (const float*)d_in[10];
    const float* ng   = (const float*)d_in[11];
    const float* nb   = (const float*)d_in[12];
    const float* f1w  = (const float*)d_in[13];
    const float* f1b  = (const float*)d_in[14];
    const float* f2w  = (const float*)d_in[15];
    const float* f2b  = (const float*)d_in[16];
    const float* rbl  = (const float*)d_in[17];
    const float* ltok = (const float*)d_in[18];
    const float* lbias= (const float*)d_in[19];
    const float* pw   = (const float*)d_in[20];
    const float* pb   = (const float*)d_in[21];
    const int*   rpi  = (const int*)d_in[22];

    const int C = 256, Hh = 64, Ww = 64, Nn = Hh * Ww;
    const int B = in_sizes[0] / (Nn * C);   // 4
    const int T = in_sizes[1] / 2;
    const int M = B * Nn;                   // 16384

    float* ws = (float*)d_ws;
    size_t o = 0;
    ushort_t* qh    = (ushort_t*)(ws + o); o += (size_t)M * C / 2;     // fp16 q
    ushort_t* kvh   = (ushort_t*)(ws + o); o += (size_t)M * C;         // fp16 M x 512
    ushort_t* xsrh  = (ushort_t*)(ws + o); o += (size_t)M * C / 2;     // fp16 xsr
    ushort_t* xpoolh= (ushort_t*)(ws + o); o += (size_t)B * 64 * C / 2;// fp16 x_pool
    ushort_t* kvph  = (ushort_t*)(ws + o); o += (size_t)B * 64 * C;    // fp16 (B,64,512)
    float* cpbB  = ws + o; o += (size_t)T * 8;
    ushort_t* xh   = (ushort_t*)(ws + o); o += (size_t)M * C / 2;      // fp16 x; reused as attno
    ushort_t* Wall = (ushort_t*)(ws + o); o += 1024 * 256 / 2;
    ushort_t* Pwh  = (ushort_t*)(ws + o); o += 256 * 256 / 2;
    float* ball = ws + o; o += 1024;
    ushort_t* attno_hf = xh;   // xh dead after the x-GEMM

    dim3 blk(256);
    const int n4x = M * C / 4;
    const int nprep = (n4x + 255) / 256;    // 4096
    const int ncpb  = (T + 3) / 4;

    // prep (cast x + pack weights) + cpb MLP, one kernel
    prep_cpb<<<nprep + ncpb, blk, 0, stream>>>(
        (const float4*)x, (ushort4*)xh, n4x,
        nprep, q_w, kv_w, sr_w, pw, q_b, kv_b, sr_b, Wall, Pwh, ball,
        tbl, f1w, f1b, f2w, f2b, cpbB, T);
    // fused [q | k(norm) | v | sr(gelu)] fp16 GEMM, 128x128 tile
    mfma_hgemm<128, 128><<<dim3(8, M / 128), blk, 0, stream>>>(
        xh, Wall, ball, nullptr, qh, kvh, xsrh, 0);
    // pool + LN (fp16 out)
    pool_ln<<<B * 64, blk, 0, stream>>>(xsrh, ng, nb, xpoolh, Hh, Ww);
    // kv_p fp16 MFMA GEMM with fused k_pool head-norm
    mfma_hgemm<64, 64><<<dim3(8, (B * 64) / 64), blk, 0, stream>>>(
        xpoolh, Wall + 256 * 256, ball + 256, nullptr, nullptr, kvph, nullptr, 2);
    // attention (fp16 in/out; bias gathered in-kernel)
    attn_v8<<<dim3(64, 8, B), blk, 0, stream>>>(
        qh, kvh, kvph, rpi, cpbB, sls, temp, qe, rbl, ltok, lbias, attno_hf);
    // proj fp16 GEMM
    mfma_hgemm<64, 64><<<dim3(4, M / 64), blk, 0, stream>>>(
        attno_hf, Pwh, pb, (float*)d_out, nullptr, nullptr, nullptr, 1);
}

// Round 3
// 207.984 us; speedup vs baseline: 1.1016x; 1.1016x over previous
//
#include <hip/hip_runtime.h>
#include <math.h>

// ---------------------------------------------------------------------------
// TransNeXt aggregated attention. Round 14:
//  - GEMM K-loop rebuilt as counted-vmcnt pipeline (T3/T4): raw s_barrier,
//    s_waitcnt vmcnt(LPS) (never 0 in-loop), depth-2 double buffer. The R13
//    __syncthreads() version drained vmcnt(0) every K-step (the m97 stall).
//  - s_setprio(1) around MFMA cluster (T5; pays once phases are split).
//  - Bijective XCD chunk-swizzle of block index (T1) -> A/B panel L2 reuse.
//  - x-GEMM tile back to 128x64 (2048 blocks, 24 KB LDS, more TLP).
//  6 dispatches.
// B=4, H=W=64, C=256, NH=8, hd=32, LOCAL_LEN=9, pool 8x8=64
// ---------------------------------------------------------------------------

typedef unsigned short ushort_t;
typedef __attribute__((ext_vector_type(8))) _Float16 half8;
typedef __attribute__((ext_vector_type(2))) _Float16 half2_t;
typedef __attribute__((ext_vector_type(4))) float f32x4;

static __device__ __forceinline__ ushort_t f2h(float f) {
    _Float16 h = (_Float16)f;           // RTNE
    return *(ushort_t*)&h;
}

static __device__ __forceinline__ float fdot2f(half2_t a, half2_t b, float c) {
#if __has_builtin(__builtin_amdgcn_fdot2)
    return __builtin_amdgcn_fdot2(a, b, c, false);
#else
    return (float)a[0] * (float)b[0] + (float)a[1] * (float)b[1] + c;
#endif
}

// ---- DPP lane reductions (VALU pipe) --------------------------------------
template <int CTRL>
static __device__ __forceinline__ float dpp_addf(float x) {
    int v = __builtin_amdgcn_update_dpp(
        0, __builtin_bit_cast(int, x), CTRL, 0xF, 0xF, true);
    return x + __builtin_bit_cast(float, v);
}
static __device__ __forceinline__ float quad_sumf(float x) {
    return dpp_addf<0x4E>(dpp_addf<0xB1>(x));
}
static __device__ __forceinline__ float sum16f(float x) {
    return dpp_addf<0x128>(dpp_addf<0x124>(quad_sumf(x)));
}

#define GLOAD16(g, l)                                                        \
    __builtin_amdgcn_global_load_lds(                                        \
        (const __attribute__((address_space(1))) unsigned int*)(g),          \
        (__attribute__((address_space(3))) unsigned int*)(l), 16, 0, 0)

// ---------------------------------------------------------------------------
// mfma_hgemm<TM,TN>: C = A @ W^T + bias, fp16 in, fp32 accum.
// 4 waves in 2x2; wave tile (TM/2)x(TN/2). Depth-2 counted-vmcnt pipeline.
// mode 0 (x-GEMM, N=1024): col<256 -> qh fp16; col<512 -> kvh k fp16 with
//   FUSED per-head L2 norm; col<768 -> kvh v fp16; else gelu -> xsrh fp16
// mode 1 (proj, N=256): out0 fp32
// mode 2 (kv_p, N=512): kvh (stride 512) fp16; col<256 fused per-head L2 norm
//
// LDS swizzle: logical (row, 16B-slot s) at phys slot s ^ ((row>>1)&3);
// stage keeps LDS dest linear (global_load_lds constraint) and pre-swizzles
// the GLOBAL source column; reads apply the same XOR. Conflict-free (R13:
// SQ_LDS_BANK_CONFLICT = 0).
//
// Pipeline correctness: s_waitcnt vmcnt(LPS) -> my stage-s loads done
// (FIFO, m135); s_barrier -> ALL waves' stage-s loads done; MFMAs consume
// every ds_read before barrier#2 (compiler lgkmcnt), so re-staging the same
// buffer after barrier#2 is race-free. vmcnt never drains to 0 in-loop.
// ---------------------------------------------------------------------------
template <int TM, int TN>
__global__ __launch_bounds__(256) void mfma_hgemm(
    const ushort_t* __restrict__ Ag, const ushort_t* __restrict__ Bg,
    const float* __restrict__ bias, float* __restrict__ out0,
    ushort_t* __restrict__ qh_out, ushort_t* __restrict__ kvh,
    ushort_t* __restrict__ xsrh, int mode)
{
    const int K = 256;
    const int IM = TM / 32;
    const int JN = TN / 32;
    constexpr int LPS = TM / 64 + TN / 64;   // global_load_lds per thread/stage
    __shared__ ushort_t Ah[2][TM * 32];
    __shared__ ushort_t Bh[2][TN * 32];

    const int t = threadIdx.x;
    const int w = t >> 6;
    const int lane = t & 63;

    // --- XCD-aware bijective chunk swizzle (all our grids are %8 == 0) ----
    const int nwg = gridDim.x * gridDim.y;
    int wg = blockIdx.y * gridDim.x + blockIdx.x;
    wg = (wg & 7) * (nwg >> 3) + (wg >> 3);
    const int bm = (wg / gridDim.x) * TM;
    const int bn = (wg % gridDim.x) * TN;

    const int wm = (w >> 1) * (TM / 2);
    const int wn = (w & 1) * (TN / 2);

    f32x4 acc[IM][JN];
#pragma unroll
    for (int i = 0; i < IM; ++i)
#pragma unroll
        for (int j = 0; j < JN; ++j) acc[i][j] = f32x4{0.f, 0.f, 0.f, 0.f};

    const int lrow  = t >> 2;
    const int lk8sw = ((t & 3) ^ ((t >> 3) & 3)) * 8;  // pre-swizzled src col

#define STAGE(bufi, k0s)                                                     \
    do {                                                                     \
        _Pragma("unroll")                                                    \
        for (int r = 0; r < TM / 64; ++r)                                    \
            GLOAD16(Ag + (size_t)(bm + r * 64 + lrow) * K + (k0s) + lk8sw,   \
                    &Ah[bufi][(unsigned)(r * 64 + w * 16) * 32]);            \
        _Pragma("unroll")                                                    \
        for (int r = 0; r < TN / 64; ++r)                                    \
            GLOAD16(Bg + (size_t)(bn + r * 64 + lrow) * K + (k0s) + lk8sw,   \
                    &Bh[bufi][(unsigned)(r * 64 + w * 16) * 32]);            \
    } while (0)

    const int fr   = lane & 15;
    const int sws8 = ((lane >> 4) ^ ((fr >> 1) & 3)) * 8;  // swizzled read slot

#define COMPUTE(bufi)                                                        \
    do {                                                                     \
        half8 af[IM], bf[JN];                                                \
        _Pragma("unroll")                                                    \
        for (int i2 = 0; i2 < IM; ++i2)                                      \
            af[i2] = *(const half8*)&Ah[bufi][(unsigned)(wm + i2 * 16 + fr) * 32 + sws8]; \
        _Pragma("unroll")                                                    \
        for (int j2 = 0; j2 < JN; ++j2)                                      \
            bf[j2] = *(const half8*)&Bh[bufi][(unsigned)(wn + j2 * 16 + fr) * 32 + sws8]; \
        __builtin_amdgcn_s_setprio(1);                                       \
        _Pragma("unroll")                                                    \
        for (int i2 = 0; i2 < IM; ++i2)                                      \
            _Pragma("unroll")                                                \
            for (int j2 = 0; j2 < JN; ++j2)                                  \
                acc[i2][j2] = __builtin_amdgcn_mfma_f32_16x16x32_f16(        \
                    af[i2], bf[j2], acc[i2][j2], 0, 0, 0);                   \
        __builtin_amdgcn_s_setprio(0);                                       \
    } while (0)

    STAGE(0, 0);
    STAGE(1, 32);
    int buf = 0;
#pragma unroll
    for (int s = 0; s < K / 32 - 1; ++s) {
        asm volatile("s_waitcnt vmcnt(%0)" :: "n"(LPS) : "memory");
        __builtin_amdgcn_s_barrier();
        asm volatile("" ::: "memory");
        COMPUTE(buf);
        asm volatile("" ::: "memory");
        __builtin_amdgcn_s_barrier();
        asm volatile("" ::: "memory");
        if (s + 2 < K / 32) STAGE(buf, (s + 2) * 32);
        buf ^= 1;
    }
    asm volatile("s_waitcnt vmcnt(0)" ::: "memory");
    __builtin_amdgcn_s_barrier();
    asm volatile("" ::: "memory");
    COMPUTE(buf);
#undef COMPUTE
#undef STAGE

    // epilogue: C/D layout col=lane&15, row=(lane>>4)*4+reg.
    // A 32-col (jp) group is one head; sum16f over the 16-lane row covers
    // its 32 cols at uniform output row -> fused L2 norm.
    const int q4 = (lane >> 4) * 4;
#pragma unroll
    for (int i = 0; i < IM; ++i) {
#pragma unroll
        for (int jp = 0; jp < JN / 2; ++jp) {
#pragma unroll
            for (int r = 0; r < 4; ++r) {
                const int row = bm + wm + i * 16 + q4 + r;
                const int col0 = bn + wn + jp * 32 + fr;
                const int col1 = col0 + 16;
                float v0 = acc[i][2 * jp][r] + bias[col0];
                float v1 = acc[i][2 * jp + 1][r] + bias[col1];
                if (mode == 0) {
                    if (col0 < 256) {
                        qh_out[(size_t)row * 256 + col0] = f2h(v0);
                        qh_out[(size_t)row * 256 + col1] = f2h(v1);
                    } else if (col0 < 512) {   // k: fused per-head L2 norm
                        const float ss = sum16f(v0 * v0 + v1 * v1);
                        const float invn = 1.0f / fmaxf(sqrtf(ss), 1e-12f);
                        kvh[(size_t)row * 512 + (col0 - 256)] = f2h(v0 * invn);
                        kvh[(size_t)row * 512 + (col1 - 256)] = f2h(v1 * invn);
                    } else if (col0 < 768) {   // v
                        kvh[(size_t)row * 512 + (col0 - 256)] = f2h(v0);
                        kvh[(size_t)row * 512 + (col1 - 256)] = f2h(v1);
                    } else {                    // sr + gelu
                        v0 = 0.5f * v0 * (1.0f + erff(v0 * 0.70710678118654752f));
                        v1 = 0.5f * v1 * (1.0f + erff(v1 * 0.70710678118654752f));
                        xsrh[(size_t)row * 256 + (col0 - 768)] = f2h(v0);
                        xsrh[(size_t)row * 256 + (col1 - 768)] = f2h(v1);
                    }
                } else if (mode == 2) {         // kv_p: fp16 out, stride 512
                    if (col0 < 256) {           // k_pool: fused per-head norm
                        const float ss = sum16f(v0 * v0 + v1 * v1);
                        const float invn = 1.0f / fmaxf(sqrtf(ss), 1e-12f);
                        v0 *= invn; v1 *= invn;
                    }
                    kvh[(size_t)row * 512 + col0] = f2h(v0);
                    kvh[(size_t)row * 512 + col1] = f2h(v1);
                } else {
                    out0[(size_t)row * 256 + col0] = v0;
                    out0[(size_t)row * 256 + col1] = v1;
                }
            }
        }
    }
}

// prep_cpb: x fp32->fp16 cast + weight/bias packing + cpb MLP in one kernel.
// Blocks [0, nprep): prep. Blocks [nprep, nprep+ncpb): cpb (wave per row).
__global__ __launch_bounds__(256) void prep_cpb(
    const float4* __restrict__ x, ushort4* __restrict__ xh, int n4, int nprep,
    const float* __restrict__ qw, const float* __restrict__ kvw,
    const float* __restrict__ srw, const float* __restrict__ pw,
    const float* __restrict__ qb, const float* __restrict__ kvb,
    const float* __restrict__ srb,
    ushort_t* __restrict__ Wall, ushort_t* __restrict__ Pw,
    float* __restrict__ ball,
    const float* __restrict__ table, const float* __restrict__ w1,
    const float* __restrict__ b1, const float* __restrict__ w2,
    const float* __restrict__ b2, float* __restrict__ outc, int T)
{
    if (blockIdx.x >= nprep) {
        const int wv = threadIdx.x >> 6;
        const int lane = threadIdx.x & 63;
        const int row = (blockIdx.x - nprep) * 4 + wv;
        if (row >= T) return;
        const float t0 = table[(size_t)row * 2];
        const float t1 = table[(size_t)row * 2 + 1];
        const int base = lane * 8;

        const float4* w1p = (const float4*)(w1 + (size_t)base * 2);
        float4 wa = w1p[0], wb = w1p[1], wc = w1p[2], wd = w1p[3];
        float4 ba = *(const float4*)(b1 + base);
        float4 bb = *(const float4*)(b1 + base + 4);
        float h[8];
        h[0] = fmaxf(fmaf(t1, wa.y, fmaf(t0, wa.x, ba.x)), 0.f);
        h[1] = fmaxf(fmaf(t1, wa.w, fmaf(t0, wa.z, ba.y)), 0.f);
        h[2] = fmaxf(fmaf(t1, wb.y, fmaf(t0, wb.x, ba.z)), 0.f);
        h[3] = fmaxf(fmaf(t1, wb.w, fmaf(t0, wb.z, ba.w)), 0.f);
        h[4] = fmaxf(fmaf(t1, wc.y, fmaf(t0, wc.x, bb.x)), 0.f);
        h[5] = fmaxf(fmaf(t1, wc.w, fmaf(t0, wc.z, bb.y)), 0.f);
        h[6] = fmaxf(fmaf(t1, wd.y, fmaf(t0, wd.x, bb.z)), 0.f);
        h[7] = fmaxf(fmaf(t1, wd.w, fmaf(t0, wd.z, bb.w)), 0.f);

#pragma unroll
        for (int hh = 0; hh < 8; ++hh) {
            const float4* w2p = (const float4*)(w2 + (size_t)hh * 512 + base);
            float4 p0 = w2p[0], p1 = w2p[1];
            float s = h[0]*p0.x + h[1]*p0.y + h[2]*p0.z + h[3]*p0.w
                    + h[4]*p1.x + h[5]*p1.y + h[6]*p1.z + h[7]*p1.w;
#pragma unroll
            for (int off = 1; off <= 32; off <<= 1) s += __shfl_xor(s, off);
            if (lane == 0) outc[(size_t)row * 8 + hh] = s + b2[hh];
        }
        return;
    }

    int idx = blockIdx.x * 256 + threadIdx.x;
    if (idx < n4) {
        float4 v = x[idx];
        ushort4 h;
        h.x = f2h(v.x); h.y = f2h(v.y); h.z = f2h(v.z); h.w = f2h(v.w);
        xh[idx] = h;
    }
    if (idx < 262144) {
        int nn = idx >> 8, k = idx & 255;
        float a;
        if (nn < 256)      a = qw[nn * 256 + k];
        else if (nn < 768) a = kvw[(nn - 256) * 256 + k];
        else               a = srw[(nn - 768) * 256 + k];
        Wall[idx] = f2h(a);
    }
    if (idx < 65536) Pw[idx] = f2h(pw[idx]);
    if (idx < 1024) {
        float bv;
        if (idx < 256)      bv = qb[idx];
        else if (idx < 768) bv = kvb[idx - 256];
        else                bv = srb[idx - 768];
        ball[idx] = bv;
    }
}

// 8x8 average pool of x_sr fp16 (B,N,C) + LayerNorm -> xpool fp16 (B,64,C)
__global__ __launch_bounds__(256) void pool_ln(
    const ushort_t* __restrict__ xsr, const float* __restrict__ g,
    const float* __restrict__ be, ushort_t* __restrict__ xpool, int Hh, int Ww)
{
    const int C = 256;
    const int Nn = Hh * Ww;
    int b = blockIdx.x >> 6;
    int pidx = blockIdx.x & 63;
    int ph = pidx >> 3, pw = pidx & 7;
    int tid = threadIdx.x;
    float s = 0.f;
    for (int si = 0; si < 8; ++si) {
        int i = ph * 8 + si;
        const ushort_t* rowp = xsr + ((size_t)b * Nn + (size_t)i * Ww + pw * 8) * C + tid;
#pragma unroll
        for (int sj = 0; sj < 8; ++sj)
            s += (float)(*(const _Float16*)&rowp[(size_t)sj * C]);
    }
    s *= (1.f / 64.f);
    __shared__ float red[256];
    red[tid] = s; __syncthreads();
    for (int st = 128; st; st >>= 1) { if (tid < st) red[tid] += red[tid + st]; __syncthreads(); }
    float mean = red[0] * (1.f / 256.f);
    __syncthreads();
    float dv = s - mean;
    red[tid] = dv * dv; __syncthreads();
    for (int st = 128; st; st >>= 1) { if (tid < st) red[tid] += red[tid + st]; __syncthreads(); }
    float var = red[0] * (1.f / 256.f);
    xpool[(size_t)blockIdx.x * C + tid] = f2h(dv * rsqrtf(var + 1e-5f) * g[tid] + be[tid]);
}

// ---------------------------------------------------------------------------
// attn_v8: lane-quad per query; fp16 q/K/V/k_pool/v_pool; DPP reductions;
// pool bias gathered per block (rpi -> cpbB) into padded LDS fp16 tile.
// ---------------------------------------------------------------------------
__global__ __launch_bounds__(256) void attn_v8(
    const ushort_t* __restrict__ qh_g, // (B,N,256) fp16 raw q
    const ushort_t* __restrict__ kvh,  // (B,N,512) fp16: k normed | v
    const ushort_t* __restrict__ kvph, // (B,64,512) fp16: k_pool normed | v_pool
    const int* __restrict__ rpi,       // (N*64) table index
    const float* __restrict__ cpbB,    // (T,8) cpb output
    const float* __restrict__ sls, const float* __restrict__ temp,
    const float* __restrict__ qe, const float* __restrict__ rbl,
    const float* __restrict__ ltok, const float* __restrict__ lbias,
    ushort_t* __restrict__ attno_hf)   // (B,N,256) fp16
{
    const int h = blockIdx.y, b = blockIdx.z;
    const int t = threadIdx.x;
    const int i = blockIdx.x;

    __shared__ half8 kp_s[64][4];
    __shared__ half8 vp_s[64][4];
    __shared__ ushort_t pb_s[64][66];   // [query j][pool p], pad 66 -> no bank conflict
    __shared__ float lts[9][32];
    __shared__ float rbl_s[9], lb_s[9], qe_s[32];

    {
        const int p = t >> 2;
        const int g4s = t & 3;
        const ushort_t* gk = kvph + ((size_t)(b * 64 + p)) * 512 + h * 32 + g4s * 8;
        kp_s[p][g4s] = *(const half8*)gk;
        vp_s[p][g4s] = *(const half8*)(gk + 256);
        const int rbase = i * 4096;
        for (int u = t; u < 4096; u += 256) {
            const int idx = rpi[rbase + u];
            pb_s[u >> 6][u & 63] = f2h(cpbB[(size_t)idx * 8 + h]);
        }
        for (int u = t; u < 288; u += 256) lts[u % 9][u / 9] = ltok[h * 288 + u];
        if (t < 9)  { rbl_s[t] = rbl[h * 9 + t]; lb_s[t] = lbias[h * 9 + t]; }
        if (t >= 64 && t < 96) qe_s[t - 64] = qe[h * 32 + (t - 64)];
    }
    __syncthreads();

    const int w = t >> 6;
    const int lane = t & 63;
    const int qi = lane >> 2;
    const int g4 = lane & 3;
    const int co = g4 * 8;
    const int j = w * 16 + qi;
    const int n = i * 64 + j;
    const size_t gq = (size_t)b * 4096 + n;

    const float tm = temp[h];
    const float sp = (tm > 20.f) ? tm : log1pf(expf(tm));

    // ---- load q slice (fp16), L2-normalize (quad DPP reduce) ----
    float qv[8];
    {
        const half8 q8 = *(const half8*)(qh_g + gq * 256 + h * 32 + co);
        float ss = 0.f;
#pragma unroll
        for (int d = 0; d < 8; ++d) { qv[d] = (float)q8[d]; ss += qv[d] * qv[d]; }
        ss = quad_sumf(ss);
        const float invn = 1.0f / fmaxf(sqrtf(ss), 1e-12f);
#pragma unroll
        for (int d = 0; d < 8; ++d) qv[d] *= invn;
    }

    // ---- learnable-token dots (fp32) ----
    float lt[9];
#pragma unroll
    for (int l = 0; l < 9; ++l) {
        float dl = 0.f;
        const float4* lw = (const float4*)&lts[l][co];
#pragma unroll
        for (int c4 = 0; c4 < 2; ++c4) {
            float4 w4 = lw[c4];
            dl += qv[4*c4+0]*w4.x + qv[4*c4+1]*w4.y + qv[4*c4+2]*w4.z + qv[4*c4+3]*w4.w;
        }
        dl = quad_sumf(dl);
        lt[l] = dl + lb_s[l];
    }

    // ---- scaled q -> fp16 pairs ----
    const float scal = sp * sls[n];
    half2_t qh[4];
#pragma unroll
    for (int c = 0; c < 4; ++c) {
        float a = (qv[2*c+0] + qe_s[co + 2*c+0]) * scal;
        float bq = (qv[2*c+1] + qe_s[co + 2*c+1]) * scal;
        qh[c] = half2_t{(_Float16)a, (_Float16)bq};
    }

    // ---- local scores (fp16 k, fdot2) ----
    float sl[9];
#pragma unroll
    for (int l = 0; l < 9; ++l) {
        const int di = l / 3 - 1, dj = l % 3 - 1;
        const int ii = i + di;
        const int jn = j + dj;
        const bool ok = (ii >= 0) && (ii < 64) && (jn >= 0) && (jn < 64);
        const int ic = max(min(ii, 63), 0);
        const int jc = max(min(jn, 63), 0);
        const half8 k8 = *(const half8*)(kvh + ((size_t)(b * 4096 + ic * 64 + jc)) * 512 + h * 32 + co);
        float dk = 0.f;
        dk = fdot2f(qh[0], __builtin_shufflevector(k8, k8, 0, 1), dk);
        dk = fdot2f(qh[1], __builtin_shufflevector(k8, k8, 2, 3), dk);
        dk = fdot2f(qh[2], __builtin_shufflevector(k8, k8, 4, 5), dk);
        dk = fdot2f(qh[3], __builtin_shufflevector(k8, k8, 6, 7), dk);
        dk = quad_sumf(dk);
        sl[l] = ok ? (dk + rbl_s[l]) : -INFINITY;
    }

    float m = sl[0];
#pragma unroll
    for (int l = 1; l < 9; ++l) m = fmaxf(m, sl[l]);

    // ---- pool: 8 chunks of 8, online softmax; AV in packed fp16 ----
    half2_t oh[4];
#pragma unroll
    for (int c = 0; c < 4; ++c) oh[c] = half2_t{(_Float16)0.f, (_Float16)0.f};
    float Z = 0.f;

    for (int cch = 0; cch < 8; ++cch) {
        float s8[8];
        float pbv[8];
#pragma unroll
        for (int c = 0; c < 4; ++c) {
            const half2_t p2 = *(const half2_t*)&pb_s[j][cch * 8 + 2 * c];
            pbv[2*c]   = (float)p2[0];
            pbv[2*c+1] = (float)p2[1];
        }
#pragma unroll
        for (int k = 0; k < 8; ++k) {
            const int p = cch * 8 + k;
            const half8 k8 = kp_s[p][g4];
            float acc = 0.f;
            acc = fdot2f(qh[0], __builtin_shufflevector(k8, k8, 0, 1), acc);
            acc = fdot2f(qh[1], __builtin_shufflevector(k8, k8, 2, 3), acc);
            acc = fdot2f(qh[2], __builtin_shufflevector(k8, k8, 4, 5), acc);
            acc = fdot2f(qh[3], __builtin_shufflevector(k8, k8, 6, 7), acc);
            acc = quad_sumf(acc);
            s8[k] = acc + pbv[k];
        }
        float cmax = s8[0];
#pragma unroll
        for (int k = 1; k < 8; ++k) cmax = fmaxf(cmax, s8[k]);
        const float m_new = fmaxf(m, cmax);
        const float factor = __expf(m - m_new);
        Z *= factor;
        const _Float16 fh = (_Float16)factor;
        const half2_t f2 = half2_t{fh, fh};
#pragma unroll
        for (int c = 0; c < 4; ++c) oh[c] *= f2;
        m = m_new;
#pragma unroll
        for (int k = 0; k < 8; ++k) {
            const float a = __expf(s8[k] - m);
            Z += a;
            const _Float16 ah = (_Float16)a;
            const half2_t a2 = half2_t{ah, ah};
            const half8 v8 = vp_s[cch * 8 + k][g4];
            oh[0] = a2 * __builtin_shufflevector(v8, v8, 0, 1) + oh[0];
            oh[1] = a2 * __builtin_shufflevector(v8, v8, 2, 3) + oh[1];
            oh[2] = a2 * __builtin_shufflevector(v8, v8, 4, 5) + oh[2];
            oh[3] = a2 * __builtin_shufflevector(v8, v8, 6, 7) + oh[3];
        }
    }

    // ---- local exps with final m ----
#pragma unroll
    for (int l = 0; l < 9; ++l) { sl[l] = __expf(sl[l] - m); Z += sl[l]; }

    // ---- local AV: coef = el + lt*Z (unnormalized; final *invZ) ----
#pragma unroll
    for (int l = 0; l < 9; ++l) {
        const int di = l / 3 - 1, dj = l % 3 - 1;
        const int ii = i + di;
        const int jn = j + dj;
        const bool ok = (ii >= 0) && (ii < 64) && (jn >= 0) && (jn < 64);
        const int ic = max(min(ii, 63), 0);
        const int jc = max(min(jn, 63), 0);
        const float coef = ok ? (sl[l] + lt[l] * Z) : 0.f;
        const half8 v8 = *(const half8*)(kvh + ((size_t)(b * 4096 + ic * 64 + jc)) * 512 + 256 + h * 32 + co);
        const _Float16 ch = (_Float16)coef;
        const half2_t c2 = half2_t{ch, ch};
        oh[0] = c2 * __builtin_shufflevector(v8, v8, 0, 1) + oh[0];
        oh[1] = c2 * __builtin_shufflevector(v8, v8, 2, 3) + oh[1];
        oh[2] = c2 * __builtin_shufflevector(v8, v8, 4, 5) + oh[2];
        oh[3] = c2 * __builtin_shufflevector(v8, v8, 6, 7) + oh[3];
    }

    // ---- normalize and store fp16 ----
    const float invZ = 1.0f / Z;
    ushort4* outp = (ushort4*)(attno_hf + gq * 256 + h * 32 + co);
#pragma unroll
    for (int c4 = 0; c4 < 2; ++c4) {
        ushort4 u;
        u.x = f2h((float)oh[2*c4+0][0] * invZ);
        u.y = f2h((float)oh[2*c4+0][1] * invZ);
        u.z = f2h((float)oh[2*c4+1][0] * invZ);
        u.w = f2h((float)oh[2*c4+1][1] * invZ);
        outp[c4] = u;
    }
}

extern "C" void kernel_launch(void* const* d_in, const int* in_sizes, int n_in,
                              void* d_out, int out_size, void* d_ws, size_t ws_size,
                              hipStream_t stream)
{
    const float* x    = (const float*)d_in[0];
    const float* tbl  = (const float*)d_in[1];
    const float* sls  = (const float*)d_in[2];
    const float* q_w  = (const float*)d_in[3];
    const float* q_b  = (const float*)d_in[4];
    const float* kv_w = (const float*)d_in[5];
    const float* kv_b = (const float*)d_in[6];
    const float* temp = (const float*)d_in[7];
    const float* qe   = (const float*)d_in[8];
    const float* sr_w = (const float*)d_in[9];
    const float* sr_b = (const float*)d_in[10];
    const float* ng   = (const float*)d_in[11];
    const float* nb   = (const float*)d_in[12];
    const float* f1w  = (const float*)d_in[13];
    const float* f1b  = (const float*)d_in[14];
    const float* f2w  = (const float*)d_in[15];
    const float* f2b  = (const float*)d_in[16];
    const float* rbl  = (const float*)d_in[17];
    const float* ltok = (const float*)d_in[18];
    const float* lbias= (const float*)d_in[19];
    const float* pw   = (const float*)d_in[20];
    const float* pb   = (const float*)d_in[21];
    const int*   rpi  = (const int*)d_in[22];

    const int C = 256, Hh = 64, Ww = 64, Nn = Hh * Ww;
    const int B = in_sizes[0] / (Nn * C);   // 4
    const int T = in_sizes[1] / 2;
    const int M = B * Nn;                   // 16384

    float* ws = (float*)d_ws;
    size_t o = 0;
    ushort_t* qh    = (ushort_t*)(ws + o); o += (size_t)M * C / 2;     // fp16 q
    ushort_t* kvh   = (ushort_t*)(ws + o); o += (size_t)M * C;         // fp16 M x 512
    ushort_t* xsrh  = (ushort_t*)(ws + o); o += (size_t)M * C / 2;     // fp16 xsr
    ushort_t* xpoolh= (ushort_t*)(ws + o); o += (size_t)B * 64 * C / 2;// fp16 x_pool
    ushort_t* kvph  = (ushort_t*)(ws + o); o += (size_t)B * 64 * C;    // fp16 (B,64,512)
    float* cpbB  = ws + o; o += (size_t)T * 8;
    ushort_t* xh   = (ushort_t*)(ws + o); o += (size_t)M * C / 2;      // fp16 x; reused as attno
    ushort_t* Wall = (ushort_t*)(ws + o); o += 1024 * 256 / 2;
    ushort_t* Pwh  = (ushort_t*)(ws + o); o += 256 * 256 / 2;
    float* ball = ws + o; o += 1024;
    ushort_t* attno_hf = xh;   // xh dead after the x-GEMM

    dim3 blk(256);
    const int n4x = M * C / 4;
    const int nprep = (n4x + 255) / 256;    // 4096
    const int ncpb  = (T + 3) / 4;

    // prep (cast x + pack weights) + cpb MLP, one kernel
    prep_cpb<<<nprep + ncpb, blk, 0, stream>>>(
        (const float4*)x, (ushort4*)xh, n4x,
        nprep, q_w, kv_w, sr_w, pw, q_b, kv_b, sr_b, Wall, Pwh, ball,
        tbl, f1w, f1b, f2w, f2b, cpbB, T);
    // fused [q | k(norm) | v | sr(gelu)] fp16 GEMM, 128x64 tile
    mfma_hgemm<128, 64><<<dim3(16, M / 128), blk, 0, stream>>>(
        xh, Wall, ball, nullptr, qh, kvh, xsrh, 0);
    // pool + LN (fp16 out)
    pool_ln<<<B * 64, blk, 0, stream>>>(xsrh, ng, nb, xpoolh, Hh, Ww);
    // kv_p fp16 MFMA GEMM with fused k_pool head-norm
    mfma_hgemm<64, 64><<<dim3(8, (B * 64) / 64), blk, 0, stream>>>(
        xpoolh, Wall + 256 * 256, ball + 256, nullptr, nullptr, kvph, nullptr, 2);
    // attention (fp16 in/out; bias gathered in-kernel)
    attn_v8<<<dim3(64, 8, B), blk, 0, stream>>>(
        qh, kvh, kvph, rpi, cpbB, sls, temp, qe, rbl, ltok, lbias, attno_hf);
    // proj fp16 GEMM
    mfma_hgemm<64, 64><<<dim3(4, M / 64), blk, 0, stream>>>(
        attno_hf, Pwh, pb, (float*)d_out, nullptr, nullptr, nullptr, 1);
}